// Round 1
// baseline (393.174 us; speedup 1.0000x reference)
//
#include <hip/hip_runtime.h>

#define HWSZ 4096
#define NTRI 136
#define NSTAT 152
#define NINST 512
#define GCNT 16
#define EPSW 1e-5f

// ---------------------------------------------------------------------------
// K1: per-instance stats. One block per (n,g) instance (512 blocks).
// Computes S1[c] = sum_p x[c][p], S2[c<=d] = sum_p x[c][p]*x[d][p].
// x layout: instance b occupies 16 contiguous channel rows of 4096 floats
// starting at float offset b*16*4096 (since n*256 + g*16 = 16*(n*16+g)).
// ---------------------------------------------------------------------------
__global__ __launch_bounds__(256) void k_inst_stats(const float* __restrict__ x,
                                                    float* __restrict__ inst_stats) {
  const int b = blockIdx.x;
  const int t = threadIdx.x;
  const float2* xb = (const float2*)x + (size_t)b * 16 * 2048;

  float s1[16];
  float s2[NTRI];
#pragma unroll
  for (int i = 0; i < 16; ++i) s1[i] = 0.f;
#pragma unroll
  for (int i = 0; i < NTRI; ++i) s2[i] = 0.f;

  for (int k = 0; k < 8; ++k) {
    const int f = t + k * 256;  // float2 index within a 2048-float2 channel row
    float2 v[16];
#pragma unroll
    for (int d = 0; d < 16; ++d) v[d] = xb[d * 2048 + f];
#pragma unroll
    for (int c = 0; c < 16; ++c) s1[c] += v[c].x + v[c].y;
    int tri = 0;
#pragma unroll
    for (int c = 0; c < 16; ++c) {
#pragma unroll
      for (int d = c; d < 16; ++d) {
        s2[tri] += v[c].x * v[d].x + v[c].y * v[d].y;
        ++tri;
      }
    }
  }

  // block reduction: wave shuffle then cross-wave via LDS
  __shared__ float red[4 * NSTAT];
  const int lane = t & 63;
  const int wv = t >> 6;
#pragma unroll
  for (int q = 0; q < 16; ++q) {
    float v = s1[q];
    for (int off = 32; off > 0; off >>= 1) v += __shfl_down(v, off);
    if (lane == 0) red[wv * NSTAT + q] = v;
  }
#pragma unroll
  for (int q = 0; q < NTRI; ++q) {
    float v = s2[q];
    for (int off = 32; off > 0; off >>= 1) v += __shfl_down(v, off);
    if (lane == 0) red[wv * NSTAT + 16 + q] = v;
  }
  __syncthreads();
  if (t < NSTAT) {
    inst_stats[(size_t)b * NSTAT + t] =
        red[t] + red[NSTAT + t] + red[2 * NSTAT + t] + red[3 * NSTAT + t];
  }
}

// ---------------------------------------------------------------------------
// K2: group (batch-whitening) stats: sum instance stats over N=32 per group.
// ---------------------------------------------------------------------------
__global__ __launch_bounds__(192) void k_group(const float* __restrict__ inst_stats,
                                               float* __restrict__ grp_stats) {
  const int g = blockIdx.x;
  const int t = threadIdx.x;
  if (t < NSTAT) {
    float s = 0.f;
    for (int n = 0; n < 32; ++n) s += inst_stats[(size_t)(n * GCNT + g) * NSTAT + t];
    grp_stats[(size_t)g * NSTAT + t] = s;
  }
}

// ---------------------------------------------------------------------------
// K3: per-instance mixing + Newton-Schulz. One block (256 thr) per instance;
// thread t owns matrix element (row=t>>4, col=t&15).
// Outputs folded affine transform: y = W' x + o, with
//   W'[r][c] = weight[g*16+r] * wm[r][c],  o[r] = bias[...] - sum_d W'[r][d]*mean[d]
// ---------------------------------------------------------------------------
__global__ __launch_bounds__(256) void k_newton(const float* __restrict__ inst_stats,
                                                const float* __restrict__ grp_stats,
                                                const float* __restrict__ swm,
                                                const float* __restrict__ swv,
                                                const float* __restrict__ weight,
                                                const float* __restrict__ bias,
                                                float* __restrict__ apply_wm,
                                                float* __restrict__ apply_ofs) {
  const int b = blockIdx.x;
  const int g = b & 15;
  const int t = threadIdx.x;
  const int r = t >> 4;
  const int c = t & 15;

  __shared__ float P[256], Qm[256], Rm[256], CN[256], Wl[256];
  __shared__ float Mm[16], Mi[16], Mb[16];

  // softmax of the two mixing weight pairs (computed redundantly per thread)
  float a0 = swm[0], a1 = swm[1];
  float mx = fmaxf(a0, a1);
  float e0 = expf(a0 - mx), e1 = expf(a1 - mx);
  const float mw0 = e0 / (e0 + e1), mw1 = e1 / (e0 + e1);
  a0 = swv[0]; a1 = swv[1];
  mx = fmaxf(a0, a1);
  e0 = expf(a0 - mx); e1 = expf(a1 - mx);
  const float vw0 = e0 / (e0 + e1), vw1 = e1 / (e0 + e1);

  const float inv_hw = 1.0f / (float)HWSZ;
  const float inv_nhw = 1.0f / (32.0f * (float)HWSZ);

  if (t < 16) {
    const float mi = inst_stats[(size_t)b * NSTAT + t] * inv_hw;
    const float mb = grp_stats[(size_t)g * NSTAT + t] * inv_nhw;
    Mi[t] = mi;
    Mb[t] = mb;
    Mm[t] = mw0 * mb + mw1 * mi;
  }
  __syncthreads();

  // covariance element for (r,c) from symmetric-triangle storage
  const int cmin = (r < c) ? r : c;
  const int cmax = (r < c) ? c : r;
  const int tri = 15 * cmin - (cmin * (cmin - 1)) / 2 + cmax + 16;
  const float cin = inst_stats[(size_t)b * NSTAT + tri] * inv_hw - Mi[r] * Mi[c];
  const float cbn = grp_stats[(size_t)g * NSTAT + tri] * inv_nhw - Mb[r] * Mb[c];
  float cov = vw0 * cbn + vw1 * cin + ((r == c) ? EPSW : 0.0f);

  Qm[t] = cov;
  __syncthreads();
  float trace = 0.f;
#pragma unroll
  for (int i = 0; i < 16; ++i) trace += Qm[i * 16 + i];
  const float rTr = 1.0f / trace;

  CN[t] = cov * rTr;
  P[t] = (r == c) ? 1.0f : 0.0f;
  __syncthreads();

  for (int it = 0; it < 5; ++it) {
    float q = 0.f;
#pragma unroll
    for (int k = 0; k < 16; ++k) q += P[r * 16 + k] * P[k * 16 + c];
    Qm[t] = q;
    __syncthreads();
    float rr = 0.f;
#pragma unroll
    for (int k = 0; k < 16; ++k) rr += Qm[r * 16 + k] * P[k * 16 + c];
    Rm[t] = rr;
    __syncthreads();
    float tt = 0.f;
#pragma unroll
    for (int k = 0; k < 16; ++k) tt += Rm[r * 16 + k] * CN[k * 16 + c];
    const float np = 1.5f * P[t] - 0.5f * tt;
    __syncthreads();
    P[t] = np;
    __syncthreads();
  }

  const float sr = sqrtf(rTr);
  const float wel = P[t] * sr * weight[g * 16 + r];
  Wl[t] = wel;
  apply_wm[(size_t)b * 256 + t] = wel;
  __syncthreads();
  if (t < 16) {
    float acc = 0.f;
#pragma unroll
    for (int d = 0; d < 16; ++d) acc += Wl[t * 16 + d] * Mm[d];
    apply_ofs[(size_t)b * 16 + t] = bias[g * 16 + t] - acc;
  }
}

// ---------------------------------------------------------------------------
// K4: apply y = W' x + o per instance. One block per instance, float4 I/O.
// ---------------------------------------------------------------------------
__global__ __launch_bounds__(256) void k_apply(const float* __restrict__ x,
                                               const float* __restrict__ apply_wm,
                                               const float* __restrict__ apply_ofs,
                                               float* __restrict__ y) {
  const int b = blockIdx.x;
  const int t = threadIdx.x;
  __shared__ float Wl[256];
  __shared__ float Ol[16];
  Wl[t] = apply_wm[(size_t)b * 256 + t];
  if (t < 16) Ol[t] = apply_ofs[(size_t)b * 16 + t];
  __syncthreads();

  const float4* xb = (const float4*)x + (size_t)b * 16 * 1024;
  float4* yb = (float4*)y + (size_t)b * 16 * 1024;
  const float4* W4 = (const float4*)Wl;

  for (int k = 0; k < 4; ++k) {
    const int f = t + k * 256;  // float4 index within 1024-float4 channel row
    float4 v[16];
#pragma unroll
    for (int d = 0; d < 16; ++d) v[d] = xb[d * 1024 + f];
#pragma unroll
    for (int cch = 0; cch < 16; ++cch) {
      const float o = Ol[cch];
      float4 acc;
      acc.x = o; acc.y = o; acc.z = o; acc.w = o;
#pragma unroll
      for (int dq = 0; dq < 4; ++dq) {
        const float4 w4 = W4[cch * 4 + dq];
        const int d0 = dq * 4;
        acc.x += w4.x * v[d0 + 0].x + w4.y * v[d0 + 1].x + w4.z * v[d0 + 2].x + w4.w * v[d0 + 3].x;
        acc.y += w4.x * v[d0 + 0].y + w4.y * v[d0 + 1].y + w4.z * v[d0 + 2].y + w4.w * v[d0 + 3].y;
        acc.z += w4.x * v[d0 + 0].z + w4.y * v[d0 + 1].z + w4.z * v[d0 + 2].z + w4.w * v[d0 + 3].z;
        acc.w += w4.x * v[d0 + 0].w + w4.y * v[d0 + 1].w + w4.z * v[d0 + 2].w + w4.w * v[d0 + 3].w;
      }
      yb[cch * 1024 + f] = acc;
    }
  }
}

// ---------------------------------------------------------------------------
extern "C" void kernel_launch(void* const* d_in, const int* in_sizes, int n_in,
                              void* d_out, int out_size, void* d_ws, size_t ws_size,
                              hipStream_t stream) {
  const float* x = (const float*)d_in[0];
  const float* swm = (const float*)d_in[1];
  const float* swv = (const float*)d_in[2];
  const float* weight = (const float*)d_in[3];
  const float* bias = (const float*)d_in[4];
  float* out = (float*)d_out;

  float* ws = (float*)d_ws;
  float* inst = ws;                          // 512*152 = 77824 floats
  float* grp = inst + (size_t)NINST * NSTAT; // 16*152  = 2432
  float* awm = grp + (size_t)GCNT * NSTAT;   // 512*256 = 131072
  float* aofs = awm + (size_t)NINST * 256;   // 512*16  = 8192
                                             // total ~878 KB of d_ws

  k_inst_stats<<<NINST, 256, 0, stream>>>(x, inst);
  k_group<<<GCNT, 192, 0, stream>>>(inst, grp);
  k_newton<<<NINST, 256, 0, stream>>>(inst, grp, swm, swv, weight, bias, awm, aofs);
  k_apply<<<NINST, 256, 0, stream>>>(x, awm, aofs, out);
}

// Round 2
// 384.055 us; speedup vs baseline: 1.0237x; 1.0237x over previous
//
#include <hip/hip_runtime.h>

#define HWSZ 4096
#define NTRI 136
#define NSTAT 152
#define NINST 512
#define GCNT 16
#define EPSW 1e-5f

typedef float v2f __attribute__((ext_vector_type(2)));

// ---------------------------------------------------------------------------
// K1: per-instance stats. One block per (n,g) instance (512 blocks).
// S1[c] = sum_p x[c][p], S2[c<=d] = sum_p x[c][p]*x[d][p].
// Instance b = 16 contiguous channel rows of 4096 floats at float ofs b*16*4096.
// NOTE: position loop is "#pragma unroll 1" — full unroll would try to keep
// 8x16 float2 loads live on top of the 152 accumulators and spill (round-1 bug).
// ---------------------------------------------------------------------------
__global__ __launch_bounds__(256, 2) void k_inst_stats(const float* __restrict__ x,
                                                       float* __restrict__ inst_stats) {
  const int b = blockIdx.x;
  const int t = threadIdx.x;
  const float2* xb = (const float2*)x + (size_t)b * 16 * 2048;

  float s1[16];
  float s2[NTRI];
#pragma unroll
  for (int i = 0; i < 16; ++i) s1[i] = 0.f;
#pragma unroll
  for (int i = 0; i < NTRI; ++i) s2[i] = 0.f;

#pragma unroll 1
  for (int k = 0; k < 8; ++k) {
    const int f = t + k * 256;  // float2 index within a 2048-float2 channel row
    float2 v[16];
#pragma unroll
    for (int d = 0; d < 16; ++d) v[d] = xb[d * 2048 + f];
#pragma unroll
    for (int c = 0; c < 16; ++c) s1[c] += v[c].x + v[c].y;
    int tri = 0;
#pragma unroll
    for (int c = 0; c < 16; ++c) {
#pragma unroll
      for (int d = c; d < 16; ++d) {
        s2[tri] += v[c].x * v[d].x + v[c].y * v[d].y;
        ++tri;
      }
    }
  }

  // block reduction: wave shuffle then cross-wave via LDS
  __shared__ float red[4 * NSTAT];
  const int lane = t & 63;
  const int wv = t >> 6;
#pragma unroll
  for (int q = 0; q < 16; ++q) {
    float v = s1[q];
    for (int off = 32; off > 0; off >>= 1) v += __shfl_down(v, off);
    if (lane == 0) red[wv * NSTAT + q] = v;
  }
#pragma unroll 1
  for (int q = 0; q < NTRI; ++q) {
    float v = s2[q];
    for (int off = 32; off > 0; off >>= 1) v += __shfl_down(v, off);
    if (lane == 0) red[wv * NSTAT + 16 + q] = v;
  }
  __syncthreads();
  if (t < NSTAT) {
    inst_stats[(size_t)b * NSTAT + t] =
        red[t] + red[NSTAT + t] + red[2 * NSTAT + t] + red[3 * NSTAT + t];
  }
}

// ---------------------------------------------------------------------------
// K2: group (batch-whitening) stats: sum instance stats over N=32 per group.
// ---------------------------------------------------------------------------
__global__ __launch_bounds__(192) void k_group(const float* __restrict__ inst_stats,
                                               float* __restrict__ grp_stats) {
  const int g = blockIdx.x;
  const int t = threadIdx.x;
  if (t < NSTAT) {
    float s = 0.f;
    for (int n = 0; n < 32; ++n) s += inst_stats[(size_t)(n * GCNT + g) * NSTAT + t];
    grp_stats[(size_t)g * NSTAT + t] = s;
  }
}

// ---------------------------------------------------------------------------
// K3: per-instance mixing + Newton-Schulz. One block (256 thr) per instance;
// thread t owns matrix element (row=t>>4, col=t&15).
// Outputs folded affine transform: y = W' x + o.
// ---------------------------------------------------------------------------
__global__ __launch_bounds__(256) void k_newton(const float* __restrict__ inst_stats,
                                                const float* __restrict__ grp_stats,
                                                const float* __restrict__ swm,
                                                const float* __restrict__ swv,
                                                const float* __restrict__ weight,
                                                const float* __restrict__ bias,
                                                float* __restrict__ apply_wm,
                                                float* __restrict__ apply_ofs) {
  const int b = blockIdx.x;
  const int g = b & 15;
  const int t = threadIdx.x;
  const int r = t >> 4;
  const int c = t & 15;

  __shared__ float P[256], Qm[256], Rm[256], CN[256], Wl[256];
  __shared__ float Mm[16], Mi[16], Mb[16];

  float a0 = swm[0], a1 = swm[1];
  float mx = fmaxf(a0, a1);
  float e0 = expf(a0 - mx), e1 = expf(a1 - mx);
  const float mw0 = e0 / (e0 + e1), mw1 = e1 / (e0 + e1);
  a0 = swv[0]; a1 = swv[1];
  mx = fmaxf(a0, a1);
  e0 = expf(a0 - mx); e1 = expf(a1 - mx);
  const float vw0 = e0 / (e0 + e1), vw1 = e1 / (e0 + e1);

  const float inv_hw = 1.0f / (float)HWSZ;
  const float inv_nhw = 1.0f / (32.0f * (float)HWSZ);

  if (t < 16) {
    const float mi = inst_stats[(size_t)b * NSTAT + t] * inv_hw;
    const float mb = grp_stats[(size_t)g * NSTAT + t] * inv_nhw;
    Mi[t] = mi;
    Mb[t] = mb;
    Mm[t] = mw0 * mb + mw1 * mi;
  }
  __syncthreads();

  const int cmin = (r < c) ? r : c;
  const int cmax = (r < c) ? c : r;
  const int tri = 15 * cmin - (cmin * (cmin - 1)) / 2 + cmax + 16;
  const float cin = inst_stats[(size_t)b * NSTAT + tri] * inv_hw - Mi[r] * Mi[c];
  const float cbn = grp_stats[(size_t)g * NSTAT + tri] * inv_nhw - Mb[r] * Mb[c];
  float cov = vw0 * cbn + vw1 * cin + ((r == c) ? EPSW : 0.0f);

  Qm[t] = cov;
  __syncthreads();
  float trace = 0.f;
#pragma unroll
  for (int i = 0; i < 16; ++i) trace += Qm[i * 16 + i];
  const float rTr = 1.0f / trace;

  CN[t] = cov * rTr;
  P[t] = (r == c) ? 1.0f : 0.0f;
  __syncthreads();

  for (int it = 0; it < 5; ++it) {
    float q = 0.f;
#pragma unroll
    for (int k = 0; k < 16; ++k) q += P[r * 16 + k] * P[k * 16 + c];
    Qm[t] = q;
    __syncthreads();
    float rr = 0.f;
#pragma unroll
    for (int k = 0; k < 16; ++k) rr += Qm[r * 16 + k] * P[k * 16 + c];
    Rm[t] = rr;
    __syncthreads();
    float tt = 0.f;
#pragma unroll
    for (int k = 0; k < 16; ++k) tt += Rm[r * 16 + k] * CN[k * 16 + c];
    const float np = 1.5f * P[t] - 0.5f * tt;
    __syncthreads();
    P[t] = np;
    __syncthreads();
  }

  const float sr = sqrtf(rTr);
  const float wel = P[t] * sr * weight[g * 16 + r];
  Wl[t] = wel;
  apply_wm[(size_t)b * 256 + t] = wel;
  __syncthreads();
  if (t < 16) {
    float acc = 0.f;
#pragma unroll
    for (int d = 0; d < 16; ++d) acc += Wl[t * 16 + d] * Mm[d];
    apply_ofs[(size_t)b * 16 + t] = bias[g * 16 + t] - acc;
  }
}

// ---------------------------------------------------------------------------
// K4: apply y = W' x + o. 8 blocks per instance (4096 blocks); each thread
// owns ONE float2 column (all 16 channels). Live set ~80 VGPRs -> 4 waves/EU.
// ---------------------------------------------------------------------------
__global__ __launch_bounds__(256, 4) void k_apply(const float* __restrict__ x,
                                                  const float* __restrict__ apply_wm,
                                                  const float* __restrict__ apply_ofs,
                                                  float* __restrict__ y) {
  const int bb = blockIdx.x;
  const int b = bb >> 3;      // instance
  const int chunk = bb & 7;   // position chunk
  const int t = threadIdx.x;

  __shared__ float Wl[256];
  __shared__ float Ol[16];
  Wl[t] = apply_wm[(size_t)b * 256 + t];
  if (t < 16) Ol[t] = apply_ofs[(size_t)b * 16 + t];
  __syncthreads();

  const v2f* xb = (const v2f*)x + (size_t)b * 16 * 2048;  // 2048 v2f per channel row
  v2f* yb = (v2f*)y + (size_t)b * 16 * 2048;
  const int f = chunk * 256 + t;  // v2f index within channel row

  v2f v[16];
#pragma unroll
  for (int d = 0; d < 16; ++d) v[d] = xb[d * 2048 + f];

#pragma unroll
  for (int cch = 0; cch < 16; ++cch) {
    const float o = Ol[cch];
    v2f acc;
    acc.x = o; acc.y = o;
#pragma unroll
    for (int d = 0; d < 16; ++d) acc += Wl[cch * 16 + d] * v[d];
    yb[cch * 2048 + f] = acc;
  }
}

// ---------------------------------------------------------------------------
extern "C" void kernel_launch(void* const* d_in, const int* in_sizes, int n_in,
                              void* d_out, int out_size, void* d_ws, size_t ws_size,
                              hipStream_t stream) {
  const float* x = (const float*)d_in[0];
  const float* swm = (const float*)d_in[1];
  const float* swv = (const float*)d_in[2];
  const float* weight = (const float*)d_in[3];
  const float* bias = (const float*)d_in[4];
  float* out = (float*)d_out;

  float* ws = (float*)d_ws;
  float* inst = ws;                          // 512*152
  float* grp = inst + (size_t)NINST * NSTAT; // 16*152
  float* awm = grp + (size_t)GCNT * NSTAT;   // 512*256
  float* aofs = awm + (size_t)NINST * 256;   // 512*16

  k_inst_stats<<<NINST, 256, 0, stream>>>(x, inst);
  k_group<<<GCNT, 192, 0, stream>>>(inst, grp);
  k_newton<<<NINST, 256, 0, stream>>>(inst, grp, swm, swv, weight, bias, awm, aofs);
  k_apply<<<NINST * 8, 256, 0, stream>>>(x, awm, aofs, out);
}

// Round 3
// 302.426 us; speedup vs baseline: 1.3001x; 1.2699x over previous
//
#include <hip/hip_runtime.h>

#define HWSZ 4096
#define NTRI 136
#define NSTAT 152
#define NINST 512
#define GCNT 16
#define EPSW 1e-5f

typedef float v2f __attribute__((ext_vector_type(2)));
typedef float v4f __attribute__((ext_vector_type(4)));

// ---------------------------------------------------------------------------
// K1: per-instance stats. One block per (n,g) instance (512 blocks).
// S1[c] = sum_p x[c][p], S2[c<=d] = sum_p x[c][p]*x[d][p].
//
// CRITICAL register discipline (history of this kernel):
//  - round 1: position loop fully unrolled -> 8x16 float2 loads live -> spill.
//  - round 2: "#pragma unroll 1" on the shuffle-reduction q-loop made s2[q]
//    dynamically indexed -> whole array demoted to SCRATCH (VGPR=124,
//    139 MB of phantom HBM writes, 171 us).
//  Rule: position loop = unroll 1; EVERY loop that indexes s1/s2 = full unroll.
// ---------------------------------------------------------------------------
__global__ __launch_bounds__(256, 2) void k_inst_stats(const float* __restrict__ x,
                                                       float* __restrict__ inst_stats) {
  const int b = blockIdx.x;
  const int t = threadIdx.x;
  const v2f* xb = (const v2f*)x + (size_t)b * 16 * 2048;

  float s1[16];
  float s2[NTRI];
#pragma unroll
  for (int i = 0; i < 16; ++i) s1[i] = 0.f;
#pragma unroll
  for (int i = 0; i < NTRI; ++i) s2[i] = 0.f;

#pragma unroll 1
  for (int k = 0; k < 8; ++k) {
    const int f = t + k * 256;  // float2 index within a 2048-float2 channel row
    v2f v[16];
#pragma unroll
    for (int d = 0; d < 16; ++d) v[d] = xb[d * 2048 + f];
#pragma unroll
    for (int c = 0; c < 16; ++c) s1[c] += v[c].x + v[c].y;
    int tri = 0;
#pragma unroll
    for (int c = 0; c < 16; ++c) {
#pragma unroll
      for (int d = c; d < 16; ++d) {
        s2[tri] += v[c].x * v[d].x + v[c].y * v[d].y;
        ++tri;
      }
    }
  }

  // block reduction: wave shuffle (FULLY UNROLLED - static s1/s2 indexing),
  // then cross-wave via LDS.
  __shared__ float red[4 * NSTAT];
  const int lane = t & 63;
  const int wv = t >> 6;
#pragma unroll
  for (int q = 0; q < 16; ++q) {
    float v = s1[q];
#pragma unroll
    for (int off = 32; off > 0; off >>= 1) v += __shfl_down(v, off);
    if (lane == 0) red[wv * NSTAT + q] = v;
  }
#pragma unroll
  for (int q = 0; q < NTRI; ++q) {
    float v = s2[q];
#pragma unroll
    for (int off = 32; off > 0; off >>= 1) v += __shfl_down(v, off);
    if (lane == 0) red[wv * NSTAT + 16 + q] = v;
  }
  __syncthreads();
  if (t < NSTAT) {
    inst_stats[(size_t)b * NSTAT + t] =
        red[t] + red[NSTAT + t] + red[2 * NSTAT + t] + red[3 * NSTAT + t];
  }
}

// ---------------------------------------------------------------------------
// K2: group (batch-whitening) stats: sum instance stats over N=32 per group.
// ---------------------------------------------------------------------------
__global__ __launch_bounds__(192) void k_group(const float* __restrict__ inst_stats,
                                               float* __restrict__ grp_stats) {
  const int g = blockIdx.x;
  const int t = threadIdx.x;
  if (t < NSTAT) {
    float s = 0.f;
    for (int n = 0; n < 32; ++n) s += inst_stats[(size_t)(n * GCNT + g) * NSTAT + t];
    grp_stats[(size_t)g * NSTAT + t] = s;
  }
}

// ---------------------------------------------------------------------------
// K3: per-instance mixing + Newton-Schulz. One block (256 thr) per instance;
// thread t owns matrix element (row=t>>4, col=t&15).
// Outputs folded affine transform: y = W' x + o.
// ---------------------------------------------------------------------------
__global__ __launch_bounds__(256) void k_newton(const float* __restrict__ inst_stats,
                                                const float* __restrict__ grp_stats,
                                                const float* __restrict__ swm,
                                                const float* __restrict__ swv,
                                                const float* __restrict__ weight,
                                                const float* __restrict__ bias,
                                                float* __restrict__ apply_wm,
                                                float* __restrict__ apply_ofs) {
  const int b = blockIdx.x;
  const int g = b & 15;
  const int t = threadIdx.x;
  const int r = t >> 4;
  const int c = t & 15;

  __shared__ float P[256], Qm[256], Rm[256], CN[256], Wl[256];
  __shared__ float Mm[16], Mi[16], Mb[16];

  float a0 = swm[0], a1 = swm[1];
  float mx = fmaxf(a0, a1);
  float e0 = expf(a0 - mx), e1 = expf(a1 - mx);
  const float mw0 = e0 / (e0 + e1), mw1 = e1 / (e0 + e1);
  a0 = swv[0]; a1 = swv[1];
  mx = fmaxf(a0, a1);
  e0 = expf(a0 - mx); e1 = expf(a1 - mx);
  const float vw0 = e0 / (e0 + e1), vw1 = e1 / (e0 + e1);

  const float inv_hw = 1.0f / (float)HWSZ;
  const float inv_nhw = 1.0f / (32.0f * (float)HWSZ);

  if (t < 16) {
    const float mi = inst_stats[(size_t)b * NSTAT + t] * inv_hw;
    const float mb = grp_stats[(size_t)g * NSTAT + t] * inv_nhw;
    Mi[t] = mi;
    Mb[t] = mb;
    Mm[t] = mw0 * mb + mw1 * mi;
  }
  __syncthreads();

  const int cmin = (r < c) ? r : c;
  const int cmax = (r < c) ? c : r;
  const int tri = 15 * cmin - (cmin * (cmin - 1)) / 2 + cmax + 16;
  const float cin = inst_stats[(size_t)b * NSTAT + tri] * inv_hw - Mi[r] * Mi[c];
  const float cbn = grp_stats[(size_t)g * NSTAT + tri] * inv_nhw - Mb[r] * Mb[c];
  float cov = vw0 * cbn + vw1 * cin + ((r == c) ? EPSW : 0.0f);

  Qm[t] = cov;
  __syncthreads();
  float trace = 0.f;
#pragma unroll
  for (int i = 0; i < 16; ++i) trace += Qm[i * 16 + i];
  const float rTr = 1.0f / trace;

  CN[t] = cov * rTr;
  P[t] = (r == c) ? 1.0f : 0.0f;
  __syncthreads();

  for (int it = 0; it < 5; ++it) {
    float q = 0.f;
#pragma unroll
    for (int k = 0; k < 16; ++k) q += P[r * 16 + k] * P[k * 16 + c];
    Qm[t] = q;
    __syncthreads();
    float rr = 0.f;
#pragma unroll
    for (int k = 0; k < 16; ++k) rr += Qm[r * 16 + k] * P[k * 16 + c];
    Rm[t] = rr;
    __syncthreads();
    float tt = 0.f;
#pragma unroll
    for (int k = 0; k < 16; ++k) tt += Rm[r * 16 + k] * CN[k * 16 + c];
    const float np = 1.5f * P[t] - 0.5f * tt;
    __syncthreads();
    P[t] = np;
    __syncthreads();
  }

  const float sr = sqrtf(rTr);
  const float wel = P[t] * sr * weight[g * 16 + r];
  Wl[t] = wel;
  apply_wm[(size_t)b * 256 + t] = wel;
  __syncthreads();
  if (t < 16) {
    float acc = 0.f;
#pragma unroll
    for (int d = 0; d < 16; ++d) acc += Wl[t * 16 + d] * Mm[d];
    apply_ofs[(size_t)b * 16 + t] = bias[g * 16 + t] - acc;
  }
}

// ---------------------------------------------------------------------------
// K4: apply y = W' x + o. 4 blocks per instance (2048 blocks); each thread
// owns ONE float4 column (all 16 channels). ~100 live VGPRs -> 4 waves/EU.
// ---------------------------------------------------------------------------
__global__ __launch_bounds__(256, 4) void k_apply(const float* __restrict__ x,
                                                  const float* __restrict__ apply_wm,
                                                  const float* __restrict__ apply_ofs,
                                                  float* __restrict__ y) {
  const int bb = blockIdx.x;
  const int b = bb >> 2;      // instance
  const int chunk = bb & 3;   // position chunk
  const int t = threadIdx.x;

  __shared__ float Wl[256];
  __shared__ float Ol[16];
  Wl[t] = apply_wm[(size_t)b * 256 + t];
  if (t < 16) Ol[t] = apply_ofs[(size_t)b * 16 + t];
  __syncthreads();

  const v4f* xb = (const v4f*)x + (size_t)b * 16 * 1024;  // 1024 v4f per channel row
  v4f* yb = (v4f*)y + (size_t)b * 16 * 1024;
  const int f = chunk * 256 + t;  // v4f index within channel row

  v4f v[16];
#pragma unroll
  for (int d = 0; d < 16; ++d) v[d] = xb[d * 1024 + f];

#pragma unroll
  for (int cch = 0; cch < 16; ++cch) {
    v4f acc = Ol[cch];
#pragma unroll
    for (int d = 0; d < 16; ++d) acc += Wl[cch * 16 + d] * v[d];
    yb[cch * 1024 + f] = acc;
  }
}

// ---------------------------------------------------------------------------
extern "C" void kernel_launch(void* const* d_in, const int* in_sizes, int n_in,
                              void* d_out, int out_size, void* d_ws, size_t ws_size,
                              hipStream_t stream) {
  const float* x = (const float*)d_in[0];
  const float* swm = (const float*)d_in[1];
  const float* swv = (const float*)d_in[2];
  const float* weight = (const float*)d_in[3];
  const float* bias = (const float*)d_in[4];
  float* out = (float*)d_out;

  float* ws = (float*)d_ws;
  float* inst = ws;                          // 512*152
  float* grp = inst + (size_t)NINST * NSTAT; // 16*152
  float* awm = grp + (size_t)GCNT * NSTAT;   // 512*256
  float* aofs = awm + (size_t)NINST * 256;   // 512*16

  k_inst_stats<<<NINST, 256, 0, stream>>>(x, inst);
  k_group<<<GCNT, 192, 0, stream>>>(inst, grp);
  k_newton<<<NINST, 256, 0, stream>>>(inst, grp, swm, swv, weight, bias, awm, aofs);
  k_apply<<<NINST * 4, 256, 0, stream>>>(x, awm, aofs, out);
}